// Round 2
// baseline (3889.529 us; speedup 1.0000x reference)
//
#include <hip/hip_runtime.h>

#define DIMC 512   // embedding dim (fixed by the problem: 512)

// ---------------------------------------------------------------------------
// Kernel 1: base embeddings.  base[n] = data_vecs[t_n, d_n] @ data_weights[t_n]
//           + data_biases[t_n].   One block per node, 256 threads, float2/thr.
// ---------------------------------------------------------------------------
__global__ __launch_bounds__(256)
void base_kernel(const float* __restrict__ data_vecs,
                 const float* __restrict__ data_weights,
                 const float* __restrict__ data_biases,
                 const int* __restrict__ data,
                 const int* __restrict__ types,
                 float* __restrict__ base,
                 int V, int VD) {
  const int n = blockIdx.x;
  const int t = threadIdx.x;
  __shared__ float sel[DIMC];
  const int ty = types[n];
  const long long idx = data[n];
  const float* src = data_vecs + ((long long)ty * V + idx) * VD;
  for (int d = t; d < VD; d += 256) sel[d] = src[d];
  __syncthreads();
  const float* W = data_weights + (long long)ty * VD * DIMC;
  const int f0 = 2 * t;
  float2 a = {0.f, 0.f};
  for (int d = 0; d < VD; ++d) {
    const float s = sel[d];
    const float2 w = *(const float2*)(W + (long long)d * DIMC + f0);
    a.x = fmaf(s, w.x, a.x);
    a.y = fmaf(s, w.y, a.y);
  }
  const float* b = data_biases + (long long)ty * DIMC;
  base[(long long)n * DIMC + f0]     = a.x + b[f0];
  base[(long long)n * DIMC + f0 + 1] = a.y + b[f0 + 1];
}

// ---------------------------------------------------------------------------
// Kernel 2: per-graph topology analysis (on device: no host readback allowed).
//   One thread per graph.  Produces: parents (post root-chain), child counts,
//   heights, child CSR (ascending child order = reference addition order),
//   1/denom, pos-ancestor path, root edge id.
// ---------------------------------------------------------------------------
__global__ void setup_kernel(const int* __restrict__ graphs,
                             const int* __restrict__ edges,
                             const int* __restrict__ pos_p,
                             int* __restrict__ par, int* __restrict__ nch,
                             int* __restrict__ hh, int* __restrict__ onp,
                             int* __restrict__ chOff, int* __restrict__ chList,
                             int* __restrict__ plist,
                             int* __restrict__ plen, int* __restrict__ eroot,
                             float* __restrict__ inv_denom,
                             int G, int N) {
  const int g = blockIdx.x * blockDim.x + threadIdx.x;
  if (g >= G) return;
  const int pos = *pos_p;
  int* P = par + g * N;
  int* C = nch + g * N;
  int* H = hh + g * N;
  int* O = onp + g * N;
  int* CO = chOff + g * (N + 1);
  int* CL = chList + g * N;
  int* L = plist + g * N;
  for (int c = 0; c < N; ++c) { P[c] = graphs[g * N + c]; C[c] = 0; H[c] = 0; O[c] = 0; }
  // roots: chain multiple roots, last becomes THE root (faithful to reference)
  int prev = -1;
  for (int i = 0; i < N; ++i)
    if (P[i] == i) { if (prev >= 0) P[prev] = i; prev = i; }
  const int root = prev;
  P[root] = -1;  // sentinel (reference uses -n)
  for (int c = 0; c < N; ++c) { const int p = P[c]; if (p >= 0) C[p]++; }
  int internal = 0;
  for (int c = 0; c < N; ++c) if (C[c] > 0) internal++;
  inv_denom[g] = 1.0f / (float)(internal + 1);
  // heights (longest path to leaf) by relaxation (loop guards chained-root case)
  for (int it = 0; it < N; ++it) {
    bool changed = false;
    for (int c = N - 1; c >= 0; --c) {
      const int p = P[c];
      if (p >= 0 && H[c] + 1 > H[p]) { H[p] = H[c] + 1; changed = true; }
    }
    if (!changed) break;
  }
  // child CSR, children in ascending index order (= reference iteration order)
  {
    int idx = 0;
    for (int p = 0; p < N; ++p) {
      CO[p] = idx;
      for (int c = 0; c < N; ++c) if (P[c] == p) CL[idx++] = c;
    }
    CO[N] = idx;
  }
  // ancestor path of pos (strict ancestors, bottom-up, ends at root)
  int pl = 0;
  int x = (pos == root) ? -1 : P[pos];
  while (x >= 0) { L[pl++] = x; O[x] = 1; x = P[x]; }
  plen[g] = pl;
  eroot[g] = (root == pos) ? -1 : edges[root];
}

// ---------------------------------------------------------------------------
// Kernel 3: fold final projection + score into u[g] = W[e_root] @ sw (per d),
//           c0[g] = b[e_root] . sw.    One block (512 thr) per graph.
// ---------------------------------------------------------------------------
__global__ __launch_bounds__(512)
void score_prep_kernel(const float* __restrict__ ew, const float* __restrict__ eb,
                       const float* __restrict__ sw_g,
                       const int* __restrict__ eroot,
                       float* __restrict__ u, float* __restrict__ c0) {
  const int g = blockIdx.x;
  const int t = threadIdx.x;
  __shared__ float sw[DIMC];
  __shared__ float red[DIMC];
  sw[t] = sw_g[t];
  __syncthreads();
  const int er = eroot[g];
  if (er < 0) { if (t == 0) c0[g] = 0.f; return; }  // pos==root fallback
  const float* row = ew + (long long)er * DIMC * DIMC + (long long)t * DIMC;
  float a = 0.f;
  for (int f = 0; f < DIMC; ++f) a = fmaf(row[f], sw[f], a);
  u[(long long)g * DIMC + t] = a;
  red[t] = eb[(long long)er * DIMC + t] * sw[t];
  __syncthreads();
  for (int s = 256; s > 0; s >>= 1) {
    if (t < s) red[t] += red[t + s];
    __syncthreads();
  }
  if (t == 0) c0[g] = red[0];
}

// ---------------------------------------------------------------------------
// Kernel 4: DATAFLOW tree pass.  One block per (g, node) = 2048 blocks x 128
//   threads, all co-resident (4096 of 8192 waves; __launch_bounds__(128,4)
//   caps VGPR so 8 blocks/CU always fit -> no deadlock).  Each block spins on
//   its children's ready flags (device-scope atomics + agent fences = the
//   defined cross-XCD publication path), gathers their contribs, finalizes
//   emb = leaf? base : relu((base + sum children)*inv), then publishes
//   contrib[c] = emb @ W[edges[c]] + b[edges[c]].  No atomic float adds, no
//   level lockstep: critical path = tree depth, not node count.
//   Path-ancestor nodes exit immediately (pass2's job); pos is finalized here
//   (epos) but publishes no contrib.
// ---------------------------------------------------------------------------
struct P1Args {
  const float* base; float* epos; float* contrib;
  const float* ew; const float* eb;
  const int* par; const int* nch; const int* onp;
  const int* chOff; const int* chList;
  const int* edges; const float* invd; const int* pos_p;
  int* ready;
  int G, N;
};

__global__ __launch_bounds__(128, 4)
void pass1_flags(P1Args p) {
  const int b = blockIdx.x;
  const int g = b / p.N;
  const int c = b - g * p.N;
  const int gi = g * p.N + c;
  if (p.onp[gi]) return;                 // path node: finalized per-e in pass2
  const int t = threadIdx.x;
  const int f0 = 4 * t;
  __shared__ float v[DIMC];
  const int pos = *p.pos_p;
  const int pr = p.par[gi];
  const float inv = p.invd[g];
  const int cs   = p.chOff[g * (p.N + 1) + c];
  const int cend = p.chOff[g * (p.N + 1) + c + 1];

  // ---- wait until all children have published (acquire, device scope) ----
  if (t == 0) {
    for (int k = cs; k < cend; ++k) {
      const int ch = p.chList[g * p.N + k];
      while (__hip_atomic_load(p.ready + (g * p.N + ch), __ATOMIC_ACQUIRE,
                               __HIP_MEMORY_SCOPE_AGENT) == 0)
        __builtin_amdgcn_s_sleep(2);
    }
  }
  __syncthreads();
  __threadfence();   // agent-scope acquire side: invalidate stale cache lines

  // ---- finalize this node's embedding into LDS ----
  const float* bs = p.base + (long long)c * DIMC;
  float4 val = *(const float4*)(bs + f0);
  if (cend > cs) {
    for (int k = cs; k < cend; ++k) {
      const int ch = p.chList[g * p.N + k];
      const float4 cv =
          *(const float4*)(p.contrib + ((long long)g * p.N + ch) * DIMC + f0);
      val.x += cv.x; val.y += cv.y; val.z += cv.z; val.w += cv.w;
    }
    val.x = fmaxf(val.x * inv, 0.f);
    val.y = fmaxf(val.y * inv, 0.f);
    val.z = fmaxf(val.z * inv, 0.f);
    val.w = fmaxf(val.w * inv, 0.f);
  }
  if (c == pos)
    *(float4*)(p.epos + (long long)g * DIMC + f0) = val;
  v[f0] = val.x; v[f0 + 1] = val.y; v[f0 + 2] = val.z; v[f0 + 3] = val.w;
  __syncthreads();

  // ---- publish contribution to parent: emb @ W[e] + b[e] ----
  if (c != pos && pr >= 0) {
    const int e = p.edges[c];
    const float* W = p.ew + (long long)e * DIMC * DIMC;
    float4 a = {0.f, 0.f, 0.f, 0.f};
    #pragma unroll 16
    for (int d = 0; d < DIMC; ++d) {
      const float s = v[d];
      const float4 w = *(const float4*)(W + (long long)d * DIMC + f0);
      a.x = fmaf(s, w.x, a.x);
      a.y = fmaf(s, w.y, a.y);
      a.z = fmaf(s, w.z, a.z);
      a.w = fmaf(s, w.w, a.w);
    }
    const float4 bb = *(const float4*)(p.eb + (long long)e * DIMC + f0);
    a.x += bb.x; a.y += bb.y; a.z += bb.z; a.w += bb.w;
    *(float4*)(p.contrib + ((long long)g * p.N + c) * DIMC + f0) = a;
  }
  __syncthreads();
  if (t == 0) {
    __threadfence();   // release: write back contrib before raising the flag
    __hip_atomic_store(p.ready + gi, 1, __ATOMIC_RELEASE,
                       __HIP_MEMORY_SCOPE_AGENT);
  }
}

// ---------------------------------------------------------------------------
// Kernel 5: path pass.  One block per (g,e): walk the pos-ancestor chain,
// one matvec + sibling-contrib gather + relu per step, then epilogue dot u[g].
// ---------------------------------------------------------------------------
struct P2Args {
  const float* base; const float* epos; const float* contrib;
  const float* ew; const float* eb; const float* sw;
  const float* u; const float* c0; const float* inv_denom;
  const int* plist; const int* plen; const int* edges; const int* pos_p;
  const int* chOff; const int* chList; const int* onp;
  float* out; int G, N, E;
};

__global__ __launch_bounds__(256)
void pass2_kernel(P2Args p) {
  const int g = blockIdx.x / p.E;
  const int e = blockIdx.x - g * p.E;
  const int t = threadIdx.x;
  const int f0 = 2 * t;
  __shared__ float ce[DIMC];
  __shared__ float red[256];
  const int pos = *p.pos_p;
  const float* es = p.epos + (long long)g * DIMC;
  ce[f0] = es[f0]; ce[f0 + 1] = es[f0 + 1];
  __syncthreads();
  const int pl = p.plen[g];
  const float inv = p.inv_denom[g];
  for (int s = 0; s < pl; ++s) {
    const int pnode = p.plist[g * p.N + s];
    const int we = (s == 0) ? e : p.edges[p.plist[g * p.N + s - 1]];
    const float* W = p.ew + (long long)we * DIMC * DIMC;
    float2 a = {0.f, 0.f};
    for (int d = 0; d < DIMC; ++d) {
      const float sv = ce[d];
      const float2 w = *(const float2*)(W + (long long)d * DIMC + f0);
      a.x = fmaf(sv, w.x, a.x);
      a.y = fmaf(sv, w.y, a.y);
    }
    a.x += p.eb[(long long)we * DIMC + f0];
    a.y += p.eb[(long long)we * DIMC + f0 + 1];
    // base + sum of non-path, non-pos sibling contributions (gathered)
    const float* bs = p.base + (long long)pnode * DIMC;
    float sx = a.x + bs[f0];
    float sy = a.y + bs[f0 + 1];
    const int cs   = p.chOff[g * (p.N + 1) + pnode];
    const int cend = p.chOff[g * (p.N + 1) + pnode + 1];
    for (int k = cs; k < cend; ++k) {
      const int ch = p.chList[g * p.N + k];
      if (ch == pos || p.onp[g * p.N + ch]) continue;
      const float* cv = p.contrib + ((long long)g * p.N + ch) * DIMC;
      sx += cv[f0]; sy += cv[f0 + 1];
    }
    sx = fmaxf(sx * inv, 0.f);
    sy = fmaxf(sy * inv, 0.f);
    __syncthreads();
    ce[f0] = sx; ce[f0 + 1] = sy;
    __syncthreads();
  }
  float partial;
  if (pl > 0) {
    const float* ug = p.u + (long long)g * DIMC;
    partial = ce[f0] * ug[f0] + ce[f0 + 1] * ug[f0 + 1];
  } else {
    // pos == root: final = ce @ W_e + b_e, score = final . sw  (general fallback)
    const float* W = p.ew + (long long)e * DIMC * DIMC;
    float2 a = {0.f, 0.f};
    for (int d = 0; d < DIMC; ++d) {
      const float sv = ce[d];
      const float2 w = *(const float2*)(W + (long long)d * DIMC + f0);
      a.x = fmaf(sv, w.x, a.x);
      a.y = fmaf(sv, w.y, a.y);
    }
    a.x += p.eb[(long long)e * DIMC + f0];
    a.y += p.eb[(long long)e * DIMC + f0 + 1];
    partial = a.x * p.sw[f0] + a.y * p.sw[f0 + 1];
  }
  red[t] = partial;
  __syncthreads();
  for (int s2 = 128; s2 > 0; s2 >>= 1) {
    if (t < s2) red[t] += red[t + s2];
    __syncthreads();
  }
  if (t == 0) {
    float res = red[0] + ((pl > 0) ? p.c0[g] : 0.f);
    p.out[(long long)g * p.E + e] = res;
  }
}

// ---------------------------------------------------------------------------
extern "C" void kernel_launch(void* const* d_in, const int* in_sizes, int n_in,
                              void* d_out, int out_size, void* d_ws, size_t ws_size,
                              hipStream_t stream) {
  const float* data_vecs    = (const float*)d_in[0];
  const float* data_weights = (const float*)d_in[1];
  const float* data_biases  = (const float*)d_in[2];
  const float* edge_weights = (const float*)d_in[3];
  const float* edge_biases  = (const float*)d_in[4];
  const float* score_w      = (const float*)d_in[5];
  const int*   data   = (const int*)d_in[6];
  const int*   types  = (const int*)d_in[7];
  const int*   graphs = (const int*)d_in[8];
  const int*   edges  = (const int*)d_in[9];
  const int*   pos_p  = (const int*)d_in[10];

  const int DIM = in_sizes[5];              // 512 (score_weights is DIM x 1)
  const int T   = in_sizes[2] / DIM;        // 2
  const int E   = in_sizes[4] / DIM;        // 64
  const int N   = in_sizes[6];              // 128
  const int G   = in_sizes[8] / N;          // 16
  const int VD  = in_sizes[1] / (T * DIM);  // 512
  const int V   = in_sizes[0] / (T * VD);   // 100000
  (void)DIM; (void)n_in; (void)ws_size; (void)out_size;

  // ---- workspace carving (floats first, then int metadata) ----
  char* w = (char*)d_ws;
  float* base    = (float*)w;   w += (size_t)N * DIMC * sizeof(float);
  float* epos    = (float*)w;   w += (size_t)G * DIMC * sizeof(float);
  float* contrib = (float*)w;   w += (size_t)G * N * DIMC * sizeof(float);
  float* u       = (float*)w;   w += (size_t)G * DIMC * sizeof(float);
  float* c0      = (float*)w;   w += (size_t)G * sizeof(float);
  float* invd    = (float*)w;   w += (size_t)G * sizeof(float);
  int* par    = (int*)w;        w += (size_t)G * N * sizeof(int);
  int* nch    = (int*)w;        w += (size_t)G * N * sizeof(int);
  int* hh     = (int*)w;        w += (size_t)G * N * sizeof(int);
  int* onp    = (int*)w;        w += (size_t)G * N * sizeof(int);
  int* chOff  = (int*)w;        w += (size_t)G * (N + 1) * sizeof(int);
  int* chList = (int*)w;        w += (size_t)G * N * sizeof(int);
  int* plist  = (int*)w;        w += (size_t)G * N * sizeof(int);
  int* plen   = (int*)w;        w += (size_t)G * sizeof(int);
  int* eroot  = (int*)w;        w += (size_t)G * sizeof(int);
  int* ready  = (int*)w;        w += (size_t)G * N * sizeof(int);

  // ready flags must start at zero (ws is poisoned 0xAA before every launch)
  hipMemsetAsync(ready, 0, (size_t)G * N * sizeof(int), stream);

  base_kernel<<<N, 256, 0, stream>>>(data_vecs, data_weights, data_biases,
                                     data, types, base, V, VD);

  setup_kernel<<<1, 64, 0, stream>>>(graphs, edges, pos_p,
                                     par, nch, hh, onp, chOff, chList,
                                     plist, plen, eroot, invd, G, N);

  score_prep_kernel<<<G, 512, 0, stream>>>(edge_weights, edge_biases, score_w,
                                           eroot, u, c0);

  P1Args p1;
  p1.base = base; p1.epos = epos; p1.contrib = contrib;
  p1.ew = edge_weights; p1.eb = edge_biases;
  p1.par = par; p1.nch = nch; p1.onp = onp;
  p1.chOff = chOff; p1.chList = chList;
  p1.edges = edges; p1.invd = invd; p1.pos_p = pos_p;
  p1.ready = ready;
  p1.G = G; p1.N = N;
  pass1_flags<<<G * N, 128, 0, stream>>>(p1);

  P2Args p2;
  p2.base = base; p2.epos = epos; p2.contrib = contrib;
  p2.ew = edge_weights; p2.eb = edge_biases; p2.sw = score_w;
  p2.u = u; p2.c0 = c0; p2.inv_denom = invd;
  p2.plist = plist; p2.plen = plen; p2.edges = edges; p2.pos_p = pos_p;
  p2.chOff = chOff; p2.chList = chList; p2.onp = onp;
  p2.out = (float*)d_out; p2.G = G; p2.N = N; p2.E = E;
  pass2_kernel<<<G * E, 256, 0, stream>>>(p2);
}

// Round 3
// 1033.887 us; speedup vs baseline: 3.7620x; 3.7620x over previous
//
#include <hip/hip_runtime.h>

#define DIMC 512   // embedding dim (fixed by the problem: 512)
#define NMAX 128   // max nodes per graph (fixed by the problem: 128)

// ---------------------------------------------------------------------------
// Kernel 1: base embeddings.  base[n] = data_vecs[t_n, d_n] @ data_weights[t_n]
//           + data_biases[t_n].   One block per node, 256 threads, float2/thr.
// ---------------------------------------------------------------------------
__global__ __launch_bounds__(256)
void base_kernel(const float* __restrict__ data_vecs,
                 const float* __restrict__ data_weights,
                 const float* __restrict__ data_biases,
                 const int* __restrict__ data,
                 const int* __restrict__ types,
                 float* __restrict__ base,
                 int V, int VD) {
  const int n = blockIdx.x;
  const int t = threadIdx.x;
  __shared__ float sel[DIMC];
  const int ty = types[n];
  const long long idx = data[n];
  const float* src = data_vecs + ((long long)ty * V + idx) * VD;
  for (int d = t; d < VD; d += 256) sel[d] = src[d];
  __syncthreads();
  const float* W = data_weights + (long long)ty * VD * DIMC;
  const int f0 = 2 * t;
  float2 a = {0.f, 0.f};
  for (int d = 0; d < VD; ++d) {
    const float s = sel[d];
    const float2 w = *(const float2*)(W + (long long)d * DIMC + f0);
    a.x = fmaf(s, w.x, a.x);
    a.y = fmaf(s, w.y, a.y);
  }
  const float* b = data_biases + (long long)ty * DIMC;
  base[(long long)n * DIMC + f0]     = a.x + b[f0];
  base[(long long)n * DIMC + f0 + 1] = a.y + b[f0 + 1];
}

// ---------------------------------------------------------------------------
// Kernel 2: per-graph topology analysis — PARALLEL version.  One block per
//   graph, all arrays in LDS.  Round-2's one-thread-per-graph version was
//   1625 us (40K serial global-latency iterations); this is ~10 us.
//   Produces: parents (post root-chain), onpath, child CSR (ascending child
//   order = reference addition order), 1/denom, pos-ancestor path, root edge.
// ---------------------------------------------------------------------------
__global__ __launch_bounds__(NMAX)
void setup_kernel(const int* __restrict__ graphs,
                  const int* __restrict__ edges,
                  const int* __restrict__ pos_p,
                  int* __restrict__ par, int* __restrict__ onp,
                  int* __restrict__ chOff, int* __restrict__ chList,
                  int* __restrict__ plist,
                  int* __restrict__ plen, int* __restrict__ eroot,
                  float* __restrict__ inv_denom,
                  int G, int N) {
  const int g = blockIdx.x;
  const int t = threadIdx.x;
  __shared__ int P[NMAX], C[NMAX], O[NMAX], CO[NMAX + 1];
  __shared__ int s_root;
  if (t < N) { P[t] = graphs[g * N + t]; C[t] = 0; O[t] = 0; }
  __syncthreads();
  if (t == 0) {
    // roots: chain multiple roots, last becomes THE root (faithful to ref)
    int prev = -1;
    for (int i = 0; i < N; ++i)
      if (P[i] == i) { if (prev >= 0) P[prev] = i; prev = i; }
    s_root = prev;
    P[prev] = -1;  // sentinel (reference uses -n)
  }
  __syncthreads();
  const int root = s_root;
  if (t < N) { const int p = P[t]; if (p >= 0) atomicAdd(&C[p], 1); }
  __syncthreads();
  if (t == 0) {
    // internal-node count + exclusive prefix sum (serial over LDS: cheap)
    int internal = 0, acc = 0;
    for (int c = 0; c < N; ++c) {
      CO[c] = acc; acc += C[c];
      if (C[c] > 0) internal++;
    }
    CO[N] = acc;
    inv_denom[g] = 1.0f / (float)(internal + 1);
  }
  __syncthreads();
  // each child computes its rank among same-parent siblings (ascending order)
  if (t < N) {
    const int p = P[t];
    if (p >= 0) {
      int r = 0;
      for (int c = 0; c < t; ++c) if (P[c] == p) ++r;
      chList[g * N + CO[p] + r] = t;
    }
  }
  if (t == 0) {
    // ancestor path of pos (strict ancestors, bottom-up, ends at root)
    const int pos = *pos_p;
    int pl = 0;
    int x = (pos == root) ? -1 : P[pos];
    while (x >= 0) { plist[g * N + pl++] = x; O[x] = 1; x = P[x]; }
    plen[g] = pl;
    eroot[g] = (root == pos) ? -1 : edges[root];
  }
  __syncthreads();
  if (t < N) {
    par[g * N + t] = P[t];
    onp[g * N + t] = O[t];
    chOff[g * (N + 1) + t] = CO[t];
  }
  if (t == 0) chOff[g * (N + 1) + N] = CO[N];
}

// ---------------------------------------------------------------------------
// Kernel 3: fold final projection + score into u[g] = W[e_root] @ sw (per d),
//           c0[g] = b[e_root] . sw.    One block (512 thr) per graph.
// ---------------------------------------------------------------------------
__global__ __launch_bounds__(512)
void score_prep_kernel(const float* __restrict__ ew, const float* __restrict__ eb,
                       const float* __restrict__ sw_g,
                       const int* __restrict__ eroot,
                       float* __restrict__ u, float* __restrict__ c0) {
  const int g = blockIdx.x;
  const int t = threadIdx.x;
  __shared__ float sw[DIMC];
  __shared__ float red[DIMC];
  sw[t] = sw_g[t];
  __syncthreads();
  const int er = eroot[g];
  if (er < 0) { if (t == 0) c0[g] = 0.f; return; }  // pos==root fallback
  const float* row = ew + (long long)er * DIMC * DIMC + (long long)t * DIMC;
  float a = 0.f;
  for (int f = 0; f < DIMC; ++f) a = fmaf(row[f], sw[f], a);
  u[(long long)g * DIMC + t] = a;
  red[t] = eb[(long long)er * DIMC + t] * sw[t];
  __syncthreads();
  for (int s = 256; s > 0; s >>= 1) {
    if (t < s) red[t] += red[t + s];
    __syncthreads();
  }
  if (t == 0) c0[g] = red[0];
}

// ---------------------------------------------------------------------------
// Cross-block data movement for pass1: relaxed device-scope atomics ONLY.
// These compile to sc-bit cache-bypassing loads/stores (coherent at the agent
// coherence point across XCDs) WITHOUT buffer_wbl2/buffer_inv — the agent
// fences of the round-2 version flushed/invalidated L2 per block, evicting
// the edge_weights working set 2048 times.  Weights stay plain cached loads.
// ---------------------------------------------------------------------------
__device__ __forceinline__ float agent_ld(const float* p) {
  return __hip_atomic_load((float*)p, __ATOMIC_RELAXED, __HIP_MEMORY_SCOPE_AGENT);
}
__device__ __forceinline__ void agent_st(float* p, float v) {
  __hip_atomic_store(p, v, __ATOMIC_RELAXED, __HIP_MEMORY_SCOPE_AGENT);
}

// ---------------------------------------------------------------------------
// Kernel 4: DATAFLOW tree pass.  One block per (g, node) = 2048 blocks x 128
//   threads.  Node -> block mapping is REVERSED (c = N-1 - b%N): parents have
//   lower node index than children in these trees, so reversed mapping gives
//   children lower blockIdx -> dispatched first -> forward progress even if
//   not all blocks are co-resident.  Each block polls its children's ready
//   flags (relaxed agent atomics), gathers their contribs (relaxed agent
//   atomic loads), finalizes emb = leaf? base : relu((base+sum)*inv), then
//   publishes contrib = emb @ W[edges[c]] + b[edges[c]] (relaxed agent atomic
//   stores) and raises its flag after s_waitcnt vmcnt(0).  No fences.
//   Path-ancestor nodes exit immediately (pass2's job); pos is finalized here
//   (epos) but publishes no contrib.
// ---------------------------------------------------------------------------
struct P1Args {
  const float* base; float* epos; float* contrib;
  const float* ew; const float* eb;
  const int* par; const int* onp;
  const int* chOff; const int* chList;
  const int* edges; const float* invd; const int* pos_p;
  int* ready;
  int G, N;
};

__global__ __launch_bounds__(128, 4)
void pass1_flags(P1Args p) {
  const int b = blockIdx.x;
  const int g = b / p.N;
  const int c = p.N - 1 - (b - g * p.N);   // reversed: children dispatch first
  const int gi = g * p.N + c;
  if (p.onp[gi]) return;                 // path node: finalized per-e in pass2
  const int t = threadIdx.x;
  const int f0 = 4 * t;
  __shared__ float v[DIMC];
  const int pos = *p.pos_p;
  const int pr = p.par[gi];
  const float inv = p.invd[g];
  const int cs   = p.chOff[g * (p.N + 1) + c];
  const int cend = p.chOff[g * (p.N + 1) + c + 1];

  // ---- wait until all children have published (relaxed poll; leaves skip) --
  if (cend > cs) {
    if (t == 0) {
      for (int k = cs; k < cend; ++k) {
        const int ch = p.chList[g * p.N + k];
        while (__hip_atomic_load(p.ready + (g * p.N + ch), __ATOMIC_RELAXED,
                                 __HIP_MEMORY_SCOPE_AGENT) == 0)
          __builtin_amdgcn_s_sleep(2);
      }
    }
    __syncthreads();   // barrier (+implied waitcnt) orders poll before gathers
  }

  // ---- finalize this node's embedding into LDS ----
  const float* bs = p.base + (long long)c * DIMC;
  float4 val = *(const float4*)(bs + f0);
  if (cend > cs) {
    for (int k = cs; k < cend; ++k) {
      const int ch = p.chList[g * p.N + k];
      const float* cv = p.contrib + ((long long)g * p.N + ch) * DIMC;
      val.x += agent_ld(cv + f0);
      val.y += agent_ld(cv + f0 + 1);
      val.z += agent_ld(cv + f0 + 2);
      val.w += agent_ld(cv + f0 + 3);
    }
    val.x = fmaxf(val.x * inv, 0.f);
    val.y = fmaxf(val.y * inv, 0.f);
    val.z = fmaxf(val.z * inv, 0.f);
    val.w = fmaxf(val.w * inv, 0.f);
  }
  if (c == pos)
    *(float4*)(p.epos + (long long)g * DIMC + f0) = val;
  v[f0] = val.x; v[f0 + 1] = val.y; v[f0 + 2] = val.z; v[f0 + 3] = val.w;
  __syncthreads();

  // ---- publish contribution to parent: emb @ W[e] + b[e] ----
  if (c != pos && pr >= 0) {
    const int e = p.edges[c];
    const float* W = p.ew + (long long)e * DIMC * DIMC;
    float4 a = {0.f, 0.f, 0.f, 0.f};
    #pragma unroll 8
    for (int d = 0; d < DIMC; ++d) {
      const float s = v[d];
      const float4 w = *(const float4*)(W + (long long)d * DIMC + f0);
      a.x = fmaf(s, w.x, a.x);
      a.y = fmaf(s, w.y, a.y);
      a.z = fmaf(s, w.z, a.z);
      a.w = fmaf(s, w.w, a.w);
    }
    const float4 bb = *(const float4*)(p.eb + (long long)e * DIMC + f0);
    float* cv = p.contrib + ((long long)g * p.N + c) * DIMC;
    agent_st(cv + f0,     a.x + bb.x);
    agent_st(cv + f0 + 1, a.y + bb.y);
    agent_st(cv + f0 + 2, a.z + bb.z);
    agent_st(cv + f0 + 3, a.w + bb.w);
  }
  __syncthreads();                       // implied s_waitcnt vmcnt(0) drains stores
  if (t == 0) {
    asm volatile("s_waitcnt vmcnt(0)" ::: "memory");   // belt and braces
    __hip_atomic_store(p.ready + gi, 1, __ATOMIC_RELAXED,
                       __HIP_MEMORY_SCOPE_AGENT);
  }
}

// ---------------------------------------------------------------------------
// Kernel 5: path pass.  One block per (g,e): walk the pos-ancestor chain,
// one matvec + sibling-contrib gather + relu per step, then epilogue dot u[g].
// ---------------------------------------------------------------------------
struct P2Args {
  const float* base; const float* epos; const float* contrib;
  const float* ew; const float* eb; const float* sw;
  const float* u; const float* c0; const float* inv_denom;
  const int* plist; const int* plen; const int* edges; const int* pos_p;
  const int* chOff; const int* chList; const int* onp;
  float* out; int G, N, E;
};

__global__ __launch_bounds__(256)
void pass2_kernel(P2Args p) {
  const int g = blockIdx.x / p.E;
  const int e = blockIdx.x - g * p.E;
  const int t = threadIdx.x;
  const int f0 = 2 * t;
  __shared__ float ce[DIMC];
  __shared__ float red[256];
  const int pos = *p.pos_p;
  const float* es = p.epos + (long long)g * DIMC;
  ce[f0] = es[f0]; ce[f0 + 1] = es[f0 + 1];
  __syncthreads();
  const int pl = p.plen[g];
  const float inv = p.inv_denom[g];
  for (int s = 0; s < pl; ++s) {
    const int pnode = p.plist[g * p.N + s];
    const int we = (s == 0) ? e : p.edges[p.plist[g * p.N + s - 1]];
    const float* W = p.ew + (long long)we * DIMC * DIMC;
    float2 a = {0.f, 0.f};
    for (int d = 0; d < DIMC; ++d) {
      const float sv = ce[d];
      const float2 w = *(const float2*)(W + (long long)d * DIMC + f0);
      a.x = fmaf(sv, w.x, a.x);
      a.y = fmaf(sv, w.y, a.y);
    }
    a.x += p.eb[(long long)we * DIMC + f0];
    a.y += p.eb[(long long)we * DIMC + f0 + 1];
    // base + sum of non-path, non-pos sibling contributions (gathered)
    const float* bs = p.base + (long long)pnode * DIMC;
    float sx = a.x + bs[f0];
    float sy = a.y + bs[f0 + 1];
    const int cs   = p.chOff[g * (p.N + 1) + pnode];
    const int cend = p.chOff[g * (p.N + 1) + pnode + 1];
    for (int k = cs; k < cend; ++k) {
      const int ch = p.chList[g * p.N + k];
      if (ch == pos || p.onp[g * p.N + ch]) continue;
      const float* cv = p.contrib + ((long long)g * p.N + ch) * DIMC;
      sx += cv[f0]; sy += cv[f0 + 1];
    }
    sx = fmaxf(sx * inv, 0.f);
    sy = fmaxf(sy * inv, 0.f);
    __syncthreads();
    ce[f0] = sx; ce[f0 + 1] = sy;
    __syncthreads();
  }
  float partial;
  if (pl > 0) {
    const float* ug = p.u + (long long)g * DIMC;
    partial = ce[f0] * ug[f0] + ce[f0 + 1] * ug[f0 + 1];
  } else {
    // pos == root: final = ce @ W_e + b_e, score = final . sw  (general fallback)
    const float* W = p.ew + (long long)e * DIMC * DIMC;
    float2 a = {0.f, 0.f};
    for (int d = 0; d < DIMC; ++d) {
      const float sv = ce[d];
      const float2 w = *(const float2*)(W + (long long)d * DIMC + f0);
      a.x = fmaf(sv, w.x, a.x);
      a.y = fmaf(sv, w.y, a.y);
    }
    a.x += p.eb[(long long)e * DIMC + f0];
    a.y += p.eb[(long long)e * DIMC + f0 + 1];
    partial = a.x * p.sw[f0] + a.y * p.sw[f0 + 1];
  }
  red[t] = partial;
  __syncthreads();
  for (int s2 = 128; s2 > 0; s2 >>= 1) {
    if (t < s2) red[t] += red[t + s2];
    __syncthreads();
  }
  if (t == 0) {
    float res = red[0] + ((pl > 0) ? p.c0[g] : 0.f);
    p.out[(long long)g * p.E + e] = res;
  }
}

// ---------------------------------------------------------------------------
extern "C" void kernel_launch(void* const* d_in, const int* in_sizes, int n_in,
                              void* d_out, int out_size, void* d_ws, size_t ws_size,
                              hipStream_t stream) {
  const float* data_vecs    = (const float*)d_in[0];
  const float* data_weights = (const float*)d_in[1];
  const float* data_biases  = (const float*)d_in[2];
  const float* edge_weights = (const float*)d_in[3];
  const float* edge_biases  = (const float*)d_in[4];
  const float* score_w      = (const float*)d_in[5];
  const int*   data   = (const int*)d_in[6];
  const int*   types  = (const int*)d_in[7];
  const int*   graphs = (const int*)d_in[8];
  const int*   edges  = (const int*)d_in[9];
  const int*   pos_p  = (const int*)d_in[10];

  const int DIM = in_sizes[5];              // 512 (score_weights is DIM x 1)
  const int T   = in_sizes[2] / DIM;        // 2
  const int E   = in_sizes[4] / DIM;        // 64
  const int N   = in_sizes[6];              // 128
  const int G   = in_sizes[8] / N;          // 16
  const int VD  = in_sizes[1] / (T * DIM);  // 512
  const int V   = in_sizes[0] / (T * VD);   // 100000
  (void)DIM; (void)n_in; (void)ws_size; (void)out_size;

  // ---- workspace carving (floats first, then int metadata) ----
  char* w = (char*)d_ws;
  float* base    = (float*)w;   w += (size_t)N * DIMC * sizeof(float);
  float* epos    = (float*)w;   w += (size_t)G * DIMC * sizeof(float);
  float* contrib = (float*)w;   w += (size_t)G * N * DIMC * sizeof(float);
  float* u       = (float*)w;   w += (size_t)G * DIMC * sizeof(float);
  float* c0      = (float*)w;   w += (size_t)G * sizeof(float);
  float* invd    = (float*)w;   w += (size_t)G * sizeof(float);
  int* par    = (int*)w;        w += (size_t)G * N * sizeof(int);
  int* onp    = (int*)w;        w += (size_t)G * N * sizeof(int);
  int* chOff  = (int*)w;        w += (size_t)G * (N + 1) * sizeof(int);
  int* chList = (int*)w;        w += (size_t)G * N * sizeof(int);
  int* plist  = (int*)w;        w += (size_t)G * N * sizeof(int);
  int* plen   = (int*)w;        w += (size_t)G * sizeof(int);
  int* eroot  = (int*)w;        w += (size_t)G * sizeof(int);
  int* ready  = (int*)w;        w += (size_t)G * N * sizeof(int);

  // ready flags must start at zero (ws is poisoned 0xAA before every launch)
  hipMemsetAsync(ready, 0, (size_t)G * N * sizeof(int), stream);

  base_kernel<<<N, 256, 0, stream>>>(data_vecs, data_weights, data_biases,
                                     data, types, base, V, VD);

  setup_kernel<<<G, NMAX, 0, stream>>>(graphs, edges, pos_p,
                                       par, onp, chOff, chList,
                                       plist, plen, eroot, invd, G, N);

  score_prep_kernel<<<G, 512, 0, stream>>>(edge_weights, edge_biases, score_w,
                                           eroot, u, c0);

  P1Args p1;
  p1.base = base; p1.epos = epos; p1.contrib = contrib;
  p1.ew = edge_weights; p1.eb = edge_biases;
  p1.par = par; p1.onp = onp;
  p1.chOff = chOff; p1.chList = chList;
  p1.edges = edges; p1.invd = invd; p1.pos_p = pos_p;
  p1.ready = ready;
  p1.G = G; p1.N = N;
  pass1_flags<<<G * N, 128, 0, stream>>>(p1);

  P2Args p2;
  p2.base = base; p2.epos = epos; p2.contrib = contrib;
  p2.ew = edge_weights; p2.eb = edge_biases; p2.sw = score_w;
  p2.u = u; p2.c0 = c0; p2.inv_denom = invd;
  p2.plist = plist; p2.plen = plen; p2.edges = edges; p2.pos_p = pos_p;
  p2.chOff = chOff; p2.chList = chList; p2.onp = onp;
  p2.out = (float*)d_out; p2.G = G; p2.N = N; p2.E = E;
  pass2_kernel<<<G * E, 256, 0, stream>>>(p2);
}

// Round 4
// 980.328 us; speedup vs baseline: 3.9676x; 1.0546x over previous
//
#include <hip/hip_runtime.h>

#define DIMC 512   // embedding dim (fixed by the problem: 512)
#define NMAX 128   // max nodes per graph (fixed by the problem: 128)

// ---------------------------------------------------------------------------
// Kernel 1: base embeddings.  base[n] = data_vecs[t_n, d_n] @ data_weights[t_n]
//           + data_biases[t_n].   One block per node, 256 threads, float2/thr.
// ---------------------------------------------------------------------------
__global__ __launch_bounds__(256)
void base_kernel(const float* __restrict__ data_vecs,
                 const float* __restrict__ data_weights,
                 const float* __restrict__ data_biases,
                 const int* __restrict__ data,
                 const int* __restrict__ types,
                 float* __restrict__ base,
                 int V, int VD) {
  const int n = blockIdx.x;
  const int t = threadIdx.x;
  __shared__ float sel[DIMC];
  const int ty = types[n];
  const long long idx = data[n];
  const float* src = data_vecs + ((long long)ty * V + idx) * VD;
  for (int d = t; d < VD; d += 256) sel[d] = src[d];
  __syncthreads();
  const float* W = data_weights + (long long)ty * VD * DIMC;
  const int f0 = 2 * t;
  float2 a = {0.f, 0.f};
  #pragma unroll 16
  for (int d = 0; d < VD; ++d) {
    const float s = sel[d];
    const float2 w = *(const float2*)(W + (long long)d * DIMC + f0);
    a.x = fmaf(s, w.x, a.x);
    a.y = fmaf(s, w.y, a.y);
  }
  const float* b = data_biases + (long long)ty * DIMC;
  base[(long long)n * DIMC + f0]     = a.x + b[f0];
  base[(long long)n * DIMC + f0 + 1] = a.y + b[f0 + 1];
}

// ---------------------------------------------------------------------------
// Kernel 2: per-graph topology analysis — PARALLEL version.  One block per
//   graph, all arrays in LDS.  Produces: parents (post root-chain), onpath,
//   child CSR (ascending child order = reference addition order), 1/denom,
//   pos-ancestor path, root edge.
// ---------------------------------------------------------------------------
__global__ __launch_bounds__(NMAX)
void setup_kernel(const int* __restrict__ graphs,
                  const int* __restrict__ edges,
                  const int* __restrict__ pos_p,
                  int* __restrict__ par, int* __restrict__ onp,
                  int* __restrict__ chOff, int* __restrict__ chList,
                  int* __restrict__ plist,
                  int* __restrict__ plen, int* __restrict__ eroot,
                  float* __restrict__ inv_denom,
                  int G, int N) {
  const int g = blockIdx.x;
  const int t = threadIdx.x;
  __shared__ int P[NMAX], C[NMAX], O[NMAX], CO[NMAX + 1];
  __shared__ int s_root;
  if (t < N) { P[t] = graphs[g * N + t]; C[t] = 0; O[t] = 0; }
  __syncthreads();
  if (t == 0) {
    // roots: chain multiple roots, last becomes THE root (faithful to ref)
    int prev = -1;
    for (int i = 0; i < N; ++i)
      if (P[i] == i) { if (prev >= 0) P[prev] = i; prev = i; }
    s_root = prev;
    P[prev] = -1;  // sentinel (reference uses -n)
  }
  __syncthreads();
  const int root = s_root;
  if (t < N) { const int p = P[t]; if (p >= 0) atomicAdd(&C[p], 1); }
  __syncthreads();
  if (t == 0) {
    // internal-node count + exclusive prefix sum (serial over LDS: cheap)
    int internal = 0, acc = 0;
    for (int c = 0; c < N; ++c) {
      CO[c] = acc; acc += C[c];
      if (C[c] > 0) internal++;
    }
    CO[N] = acc;
    inv_denom[g] = 1.0f / (float)(internal + 1);
  }
  __syncthreads();
  // each child computes its rank among same-parent siblings (ascending order)
  if (t < N) {
    const int p = P[t];
    if (p >= 0) {
      int r = 0;
      for (int c = 0; c < t; ++c) if (P[c] == p) ++r;
      chList[g * N + CO[p] + r] = t;
    }
  }
  if (t == 0) {
    // ancestor path of pos (strict ancestors, bottom-up, ends at root)
    const int pos = *pos_p;
    int pl = 0;
    int x = (pos == root) ? -1 : P[pos];
    while (x >= 0) { plist[g * N + pl++] = x; O[x] = 1; x = P[x]; }
    plen[g] = pl;
    eroot[g] = (root == pos) ? -1 : edges[root];
  }
  __syncthreads();
  if (t < N) {
    par[g * N + t] = P[t];
    onp[g * N + t] = O[t];
    chOff[g * (N + 1) + t] = CO[t];
  }
  if (t == 0) chOff[g * (N + 1) + N] = CO[N];
}

// ---------------------------------------------------------------------------
// Kernel 3: u[g][r] = W[e_root][r,:] . sw  and  c0[g] = b[e_root] . sw.
//   Round-3 used 16 blocks with 2KB-strided per-thread reads (latency-bound,
//   uncoalesced).  Now: G x 8 blocks, one wave per row, lanes read 256B
//   contiguous, shfl reduce.  64 rows per block, 8 rows per wave.
// ---------------------------------------------------------------------------
__global__ __launch_bounds__(512)
void score_prep_kernel(const float* __restrict__ ew, const float* __restrict__ eb,
                       const float* __restrict__ sw_g,
                       const int* __restrict__ eroot,
                       float* __restrict__ u, float* __restrict__ c0) {
  const int g = blockIdx.x >> 3;
  const int chunk = blockIdx.x & 7;
  const int t = threadIdx.x;
  const int wave = t >> 6;
  const int lane = t & 63;
  __shared__ float sw[DIMC];
  sw[t] = sw_g[t];
  __syncthreads();
  const int er = eroot[g];
  if (er < 0) { if (t == 0 && chunk == 0) c0[g] = 0.f; return; }  // pos==root
  const float* Wb = ew + (long long)er * DIMC * DIMC;
  #pragma unroll
  for (int rr = 0; rr < 8; ++rr) {
    const int r = chunk * 64 + wave * 8 + rr;
    const float* row = Wb + (long long)r * DIMC;
    float a = 0.f;
    #pragma unroll
    for (int k = 0; k < 8; ++k)
      a = fmaf(row[lane + 64 * k], sw[lane + 64 * k], a);
    #pragma unroll
    for (int off = 32; off > 0; off >>= 1) a += __shfl_down(a, off, 64);
    if (lane == 0) u[(long long)g * DIMC + r] = a;
  }
  if (chunk == 0) {
    __shared__ float red[512];
    red[t] = eb[(long long)er * DIMC + t] * sw[t];
    __syncthreads();
    for (int s = 256; s > 0; s >>= 1) {
      if (t < s) red[t] += red[t + s];
      __syncthreads();
    }
    if (t == 0) c0[g] = red[0];
  }
}

// ---------------------------------------------------------------------------
// Cross-block data movement for pass1: relaxed device-scope atomics ONLY
// (sc-bit cache-bypassing accesses; no buffer_wbl2/inv L2 flushes).
// ---------------------------------------------------------------------------
__device__ __forceinline__ float agent_ld(const float* p) {
  return __hip_atomic_load((float*)p, __ATOMIC_RELAXED, __HIP_MEMORY_SCOPE_AGENT);
}
__device__ __forceinline__ void agent_st(float* p, float v) {
  __hip_atomic_store(p, v, __ATOMIC_RELAXED, __HIP_MEMORY_SCOPE_AGENT);
}

// ---------------------------------------------------------------------------
// Kernel 4: DATAFLOW tree pass.  One block per (g, node) = 2048 blocks x 128
//   threads, all co-resident (launch_bounds(128,4) -> VGPR<=128 -> 16 waves/CU
//   -> 8 blocks/CU x 256 CU = 2048).  Reversed node->block mapping keeps
//   children ahead of parents in dispatch order as a second safety net.
//   Round-4 latency attack: (a) unroll 16 on the matvec (was the compiler's 8:
//   512 loads/thread / unroll = latency batches on the serial tree chain);
//   (b) while waiting on children, wave 1 prefetches W[edges[c]] into L1/L2
//   (touch one dword per 64B line) so the post-wait matvec runs cache-warm.
// ---------------------------------------------------------------------------
struct P1Args {
  const float* base; float* epos; float* contrib;
  const float* ew; const float* eb;
  const int* par; const int* onp;
  const int* chOff; const int* chList;
  const int* edges; const float* invd; const int* pos_p;
  int* ready;
  int G, N;
};

__global__ __launch_bounds__(128, 4)
void pass1_flags(P1Args p) {
  const int b = blockIdx.x;
  const int g = b / p.N;
  const int c = p.N - 1 - (b - g * p.N);   // reversed: children dispatch first
  const int gi = g * p.N + c;
  if (p.onp[gi]) return;                 // path node: finalized per-e in pass2
  const int t = threadIdx.x;
  const int f0 = 4 * t;
  __shared__ float v[DIMC];
  __shared__ int go;
  const int pos = *p.pos_p;
  const int pr = p.par[gi];
  const float inv = p.invd[g];
  const int cs   = p.chOff[g * (p.N + 1) + c];
  const int cend = p.chOff[g * (p.N + 1) + c + 1];
  const bool will_mm = (c != pos && pr >= 0);
  const int e = p.edges[c];
  const float* W = p.ew + (long long)e * DIMC * DIMC;

  // ---- wait until all children have published; prefetch W meanwhile ----
  if (cend > cs) {
    if (t == 0) go = 0;
    __syncthreads();
    if (t == 0) {
      for (int k = cs; k < cend; ++k) {
        const int ch = p.chList[g * p.N + k];
        while (__hip_atomic_load(p.ready + (g * p.N + ch), __ATOMIC_RELAXED,
                                 __HIP_MEMORY_SCOPE_AGENT) == 0)
          __builtin_amdgcn_s_sleep(2);
      }
      __hip_atomic_store(&go, 1, __ATOMIC_RELAXED,
                         __HIP_MEMORY_SCOPE_WORKGROUP);
    } else if (t >= 64 && will_mm) {
      // wave 1: warm W into L1/L2 (one dword per 64B line; 16384 lines total)
      float dummy = 0.f;
      const int ti = t - 64;                      // 0..63
      for (int chunk = 0; chunk < 32; ++chunk) {
        #pragma unroll
        for (int k = 0; k < 8; ++k) {
          const int line = chunk * 512 + k * 64 + ti;
          dummy += W[(long long)line * 16];
        }
        if (__hip_atomic_load(&go, __ATOMIC_RELAXED,
                              __HIP_MEMORY_SCOPE_WORKGROUP)) break;
      }
      asm volatile("" :: "v"(dummy));   // keep prefetch live (no DCE)
    }
    __syncthreads();   // barrier (+implied waitcnt) orders poll before gathers
  }

  // ---- finalize this node's embedding into LDS ----
  const float* bs = p.base + (long long)c * DIMC;
  float4 val = *(const float4*)(bs + f0);
  if (cend > cs) {
    for (int k = cs; k < cend; ++k) {
      const int ch = p.chList[g * p.N + k];
      const float* cv = p.contrib + ((long long)g * p.N + ch) * DIMC;
      val.x += agent_ld(cv + f0);
      val.y += agent_ld(cv + f0 + 1);
      val.z += agent_ld(cv + f0 + 2);
      val.w += agent_ld(cv + f0 + 3);
    }
    val.x = fmaxf(val.x * inv, 0.f);
    val.y = fmaxf(val.y * inv, 0.f);
    val.z = fmaxf(val.z * inv, 0.f);
    val.w = fmaxf(val.w * inv, 0.f);
  }
  if (c == pos)
    *(float4*)(p.epos + (long long)g * DIMC + f0) = val;
  v[f0] = val.x; v[f0 + 1] = val.y; v[f0 + 2] = val.z; v[f0 + 3] = val.w;
  __syncthreads();

  // ---- publish contribution to parent: emb @ W[e] + b[e] ----
  if (will_mm) {
    float4 a = {0.f, 0.f, 0.f, 0.f};
    #pragma unroll 16
    for (int d = 0; d < DIMC; ++d) {
      const float s = v[d];
      const float4 w = *(const float4*)(W + (long long)d * DIMC + f0);
      a.x = fmaf(s, w.x, a.x);
      a.y = fmaf(s, w.y, a.y);
      a.z = fmaf(s, w.z, a.z);
      a.w = fmaf(s, w.w, a.w);
    }
    const float4 bb = *(const float4*)(p.eb + (long long)e * DIMC + f0);
    float* cv = p.contrib + ((long long)g * p.N + c) * DIMC;
    agent_st(cv + f0,     a.x + bb.x);
    agent_st(cv + f0 + 1, a.y + bb.y);
    agent_st(cv + f0 + 2, a.z + bb.z);
    agent_st(cv + f0 + 3, a.w + bb.w);
  }
  __syncthreads();                 // implied s_waitcnt vmcnt(0) drains stores
  if (t == 0) {
    asm volatile("s_waitcnt vmcnt(0)" ::: "memory");   // belt and braces
    __hip_atomic_store(p.ready + gi, 1, __ATOMIC_RELAXED,
                       __HIP_MEMORY_SCOPE_AGENT);
  }
}

// ---------------------------------------------------------------------------
// Kernel 5: path pass.  One block per (g,e), 512 threads, split-K-4 matvec:
//   each 128-thread group covers 128 d-values for all 512 outputs (float4),
//   LDS partial reduce -> 128 loads/thread/step (was 512) -> 8 latency
//   batches on the serial path chain.  Then epilogue dot with u[g].
// ---------------------------------------------------------------------------
struct P2Args {
  const float* base; const float* epos; const float* contrib;
  const float* ew; const float* eb; const float* sw;
  const float* u; const float* c0; const float* inv_denom;
  const int* plist; const int* plen; const int* edges; const int* pos_p;
  const int* chOff; const int* chList; const int* onp;
  float* out; int G, N, E;
};

__global__ __launch_bounds__(512)
void pass2_kernel(P2Args p) {
  const int g = blockIdx.x / p.E;
  const int e = blockIdx.x - g * p.E;
  const int t = threadIdx.x;
  const int dg = t >> 7;          // 0..3 : which quarter of the d-range
  const int tl = t & 127;
  const int f0 = 4 * tl;
  __shared__ float ce[DIMC];
  __shared__ float part[4][DIMC];
  __shared__ float red[512];
  const int pos = *p.pos_p;
  ce[t] = p.epos[(long long)g * DIMC + t];
  __syncthreads();
  const int pl = p.plen[g];
  const float inv = p.inv_denom[g];
  for (int s = 0; s < pl; ++s) {
    const int pnode = p.plist[g * p.N + s];
    const int we = (s == 0) ? e : p.edges[p.plist[g * p.N + s - 1]];
    const float* W = p.ew + (long long)we * DIMC * DIMC
                   + (long long)(dg * 128) * DIMC;
    float4 a = {0.f, 0.f, 0.f, 0.f};
    #pragma unroll 16
    for (int i = 0; i < 128; ++i) {
      const float sv = ce[dg * 128 + i];
      const float4 w = *(const float4*)(W + (long long)i * DIMC + f0);
      a.x = fmaf(sv, w.x, a.x);
      a.y = fmaf(sv, w.y, a.y);
      a.z = fmaf(sv, w.z, a.z);
      a.w = fmaf(sv, w.w, a.w);
    }
    part[dg][f0]     = a.x;
    part[dg][f0 + 1] = a.y;
    part[dg][f0 + 2] = a.z;
    part[dg][f0 + 3] = a.w;
    __syncthreads();
    // combine partials + bias + base + non-path non-pos sibling contribs
    float sum = part[0][t] + part[1][t] + part[2][t] + part[3][t]
              + p.eb[(long long)we * DIMC + t]
              + p.base[(long long)pnode * DIMC + t];
    const int cs   = p.chOff[g * (p.N + 1) + pnode];
    const int cend = p.chOff[g * (p.N + 1) + pnode + 1];
    for (int k = cs; k < cend; ++k) {
      const int ch = p.chList[g * p.N + k];
      if (ch == pos || p.onp[g * p.N + ch]) continue;
      sum += p.contrib[((long long)g * p.N + ch) * DIMC + t];
    }
    sum = fmaxf(sum * inv, 0.f);
    __syncthreads();
    ce[t] = sum;
    __syncthreads();
  }
  float partial;
  if (pl > 0) {
    partial = ce[t] * p.u[(long long)g * DIMC + t];
  } else {
    // pos == root: final = ce @ W_e + b_e, score = final . sw (fallback)
    const float* W = p.ew + (long long)e * DIMC * DIMC
                   + (long long)(dg * 128) * DIMC;
    float4 a = {0.f, 0.f, 0.f, 0.f};
    #pragma unroll 16
    for (int i = 0; i < 128; ++i) {
      const float sv = ce[dg * 128 + i];
      const float4 w = *(const float4*)(W + (long long)i * DIMC + f0);
      a.x = fmaf(sv, w.x, a.x);
      a.y = fmaf(sv, w.y, a.y);
      a.z = fmaf(sv, w.z, a.z);
      a.w = fmaf(sv, w.w, a.w);
    }
    part[dg][f0]     = a.x;
    part[dg][f0 + 1] = a.y;
    part[dg][f0 + 2] = a.z;
    part[dg][f0 + 3] = a.w;
    __syncthreads();
    const float fin = part[0][t] + part[1][t] + part[2][t] + part[3][t]
                    + p.eb[(long long)e * DIMC + t];
    partial = fin * p.sw[t];
  }
  red[t] = partial;
  __syncthreads();
  for (int s2 = 256; s2 > 0; s2 >>= 1) {
    if (t < s2) red[t] += red[t + s2];
    __syncthreads();
  }
  if (t == 0) {
    p.out[(long long)g * p.E + e] = red[0] + ((pl > 0) ? p.c0[g] : 0.f);
  }
}

// ---------------------------------------------------------------------------
extern "C" void kernel_launch(void* const* d_in, const int* in_sizes, int n_in,
                              void* d_out, int out_size, void* d_ws, size_t ws_size,
                              hipStream_t stream) {
  const float* data_vecs    = (const float*)d_in[0];
  const float* data_weights = (const float*)d_in[1];
  const float* data_biases  = (const float*)d_in[2];
  const float* edge_weights = (const float*)d_in[3];
  const float* edge_biases  = (const float*)d_in[4];
  const float* score_w      = (const float*)d_in[5];
  const int*   data   = (const int*)d_in[6];
  const int*   types  = (const int*)d_in[7];
  const int*   graphs = (const int*)d_in[8];
  const int*   edges  = (const int*)d_in[9];
  const int*   pos_p  = (const int*)d_in[10];

  const int DIM = in_sizes[5];              // 512 (score_weights is DIM x 1)
  const int T   = in_sizes[2] / DIM;        // 2
  const int E   = in_sizes[4] / DIM;        // 64
  const int N   = in_sizes[6];              // 128
  const int G   = in_sizes[8] / N;          // 16
  const int VD  = in_sizes[1] / (T * DIM);  // 512
  const int V   = in_sizes[0] / (T * VD);   // 100000
  (void)DIM; (void)n_in; (void)ws_size; (void)out_size;

  // ---- workspace carving (floats first, then int metadata) ----
  char* w = (char*)d_ws;
  float* base    = (float*)w;   w += (size_t)N * DIMC * sizeof(float);
  float* epos    = (float*)w;   w += (size_t)G * DIMC * sizeof(float);
  float* contrib = (float*)w;   w += (size_t)G * N * DIMC * sizeof(float);
  float* u       = (float*)w;   w += (size_t)G * DIMC * sizeof(float);
  float* c0      = (float*)w;   w += (size_t)G * sizeof(float);
  float* invd    = (float*)w;   w += (size_t)G * sizeof(float);
  int* par    = (int*)w;        w += (size_t)G * N * sizeof(int);
  int* onp    = (int*)w;        w += (size_t)G * N * sizeof(int);
  int* chOff  = (int*)w;        w += (size_t)G * (N + 1) * sizeof(int);
  int* chList = (int*)w;        w += (size_t)G * N * sizeof(int);
  int* plist  = (int*)w;        w += (size_t)G * N * sizeof(int);
  int* plen   = (int*)w;        w += (size_t)G * sizeof(int);
  int* eroot  = (int*)w;        w += (size_t)G * sizeof(int);
  int* ready  = (int*)w;        w += (size_t)G * N * sizeof(int);

  // ready flags must start at zero (ws is poisoned 0xAA before every launch)
  hipMemsetAsync(ready, 0, (size_t)G * N * sizeof(int), stream);

  base_kernel<<<N, 256, 0, stream>>>(data_vecs, data_weights, data_biases,
                                     data, types, base, V, VD);

  setup_kernel<<<G, NMAX, 0, stream>>>(graphs, edges, pos_p,
                                       par, onp, chOff, chList,
                                       plist, plen, eroot, invd, G, N);

  score_prep_kernel<<<G * 8, 512, 0, stream>>>(edge_weights, edge_biases,
                                               score_w, eroot, u, c0);

  P1Args p1;
  p1.base = base; p1.epos = epos; p1.contrib = contrib;
  p1.ew = edge_weights; p1.eb = edge_biases;
  p1.par = par; p1.onp = onp;
  p1.chOff = chOff; p1.chList = chList;
  p1.edges = edges; p1.invd = invd; p1.pos_p = pos_p;
  p1.ready = ready;
  p1.G = G; p1.N = N;
  pass1_flags<<<G * N, 128, 0, stream>>>(p1);

  P2Args p2;
  p2.base = base; p2.epos = epos; p2.contrib = contrib;
  p2.ew = edge_weights; p2.eb = edge_biases; p2.sw = score_w;
  p2.u = u; p2.c0 = c0; p2.inv_denom = invd;
  p2.plist = plist; p2.plen = plen; p2.edges = edges; p2.pos_p = pos_p;
  p2.chOff = chOff; p2.chList = chList; p2.onp = onp;
  p2.out = (float*)d_out; p2.G = G; p2.N = N; p2.E = E;
  pass2_kernel<<<G * E, 512, 0, stream>>>(p2);
}